// Round 7
// baseline (104.832 us; speedup 1.0000x reference)
//
#include <hip/hip_runtime.h>
#include <stdint.h>

#define N_NODES 8192
#define CH      256
#define NWORDS  256                       // 8192 bits / 32 per bitmap row
#define BM_BYTES (N_NODES * NWORDS * 4)   // 8 MB
#define DEG_CAP 64                        // Poisson(16) tail: P(deg>64) ~ 1e-18 per row
#define EDGE_BLKS 512                     // 131072 edges / 256 threads

typedef short bf16x8 __attribute__((ext_vector_type(8)));
typedef float f32x4  __attribute__((ext_vector_type(4)));

static __device__ __forceinline__ unsigned short f2bf(float f) {
    union { float f; uint32_t u; } v; v.f = f;
    uint32_t r = v.u + 0x7fff + ((v.u >> 16) & 1);   // RNE
    return (unsigned short)(r >> 16);
}
static __device__ __forceinline__ uint32_t pack2bf(float lo, float hi) {
    return (uint32_t)f2bf(lo) | ((uint32_t)f2bf(hi) << 16);
}

// ---------------- edges -> dedup CSR + unique degree; tail blocks: W -> bf16 ----------------
// atomicOr return value gives exact dedup (matches scatter-ASSIGN semantics);
// cnt[r] ends as the unique out-degree of r; bitmap is write-only after this kernel.
__global__ void k_edges_wconv(const int* __restrict__ ei, uint32_t* __restrict__ bm,
                              int* __restrict__ cnt, unsigned short* __restrict__ csr,
                              int E, const float* __restrict__ W,
                              uint32_t* __restrict__ Wb) {
    int b = blockIdx.x;
    if (b < EDGE_BLKS) {
        int e = b * 256 + threadIdx.x;
        if (e >= E) return;
        int r = ei[e];        // edge_index[0][e]
        int c = ei[E + e];    // edge_index[1][e]
        uint32_t bit = 1u << (c & 31);
        uint32_t old = atomicOr(&bm[r * NWORDS + (c >> 5)], bit);
        if (!(old & bit)) {
            int p = atomicAdd(&cnt[r], 1);
            if (p < DEG_CAP) csr[r * DEG_CAP + p] = (unsigned short)c;
        }
    } else {
        int i = (b - EDGE_BLKS) * 1024 + threadIdx.x * 4;   // 64 blocks cover 256x256
        float4 wv = *(const float4*)(W + i);
        uint2 o;
        o.x = pack2bf(wv.x, wv.y);
        o.y = pack2bf(wv.z, wv.w);
        *(uint2*)(Wb + i / 2) = o;
    }
}

// ---------------- fused aggregate + GEMM ----------------
// Block b: rows [16b, 16b+16). Per row (1 wave per 2 rows): gather fp32 x rows of
// CSR neighbors with per-neighbor dis_j = rsqrt(cnt[j]+1), accumulate fp32,
// quantize once to bf16 in LDS, then MFMA GEMM vs W^T + bias.
__global__ __launch_bounds__(512) void k_agg_gemm(
    const int* __restrict__ cnt, const unsigned short* __restrict__ csr,
    const float* __restrict__ x, const unsigned short* __restrict__ Wb,
    const float* __restrict__ b1, const float* __restrict__ b2,
    float* __restrict__ out)
{
    const int tid  = threadIdx.x;
    const int bid  = blockIdx.x;
    const int lane = tid & 63;
    const int wid  = tid >> 6;              // 0..7

    __shared__ uint2 s_o1[16 * 66];         // 16 rows x 256ch bf16 (+pad) 8.4 KB

    const float4* xs = (const float4*)x;    // row j = xs[j*64 + lane]

    #pragma unroll
    for (int rr = 0; rr < 2; ++rr) {
        int rloc = wid * 2 + rr;
        int row  = bid * 16 + rloc;
        int total = cnt[row];
        if (total > DEG_CAP) total = DEG_CAP;
        float di = rsqrtf((float)(total + 1));
        // lane i holds neighbor id i (coalesced 2B) + that neighbor's dis (4B gather)
        int   nb = (lane < total) ? (int)csr[row * DEG_CAP + lane] : 0;
        int   cj = (lane < total) ? cnt[nb] : 0;
        float dj = rsqrtf((float)(cj + 1));

        float4 sv = xs[row * 64 + lane];    // self (diagonal): coefficient di
        float a0 = di * sv.x, a1 = di * sv.y, a2 = di * sv.z, a3 = di * sv.w;

        int k = 0;
        for (; k + 4 <= total; k += 4) {    // 4 independent 16B gathers in flight
            int   j0 = __shfl(nb, k),     j1 = __shfl(nb, k + 1);
            int   j2 = __shfl(nb, k + 2), j3 = __shfl(nb, k + 3);
            float d0 = __shfl(dj, k),     d1 = __shfl(dj, k + 1);
            float d2 = __shfl(dj, k + 2), d3 = __shfl(dj, k + 3);
            float4 v0 = xs[j0 * 64 + lane];
            float4 v1 = xs[j1 * 64 + lane];
            float4 v2 = xs[j2 * 64 + lane];
            float4 v3 = xs[j3 * 64 + lane];
            a0 += d0 * v0.x; a1 += d0 * v0.y; a2 += d0 * v0.z; a3 += d0 * v0.w;
            a0 += d1 * v1.x; a1 += d1 * v1.y; a2 += d1 * v1.z; a3 += d1 * v1.w;
            a0 += d2 * v2.x; a1 += d2 * v2.y; a2 += d2 * v2.z; a3 += d2 * v2.w;
            a0 += d3 * v3.x; a1 += d3 * v3.y; a2 += d3 * v3.z; a3 += d3 * v3.w;
        }
        for (; k < total; ++k) {
            int   j = __shfl(nb, k);
            float d = __shfl(dj, k);
            float4 v = xs[j * 64 + lane];
            a0 += d * v.x; a1 += d * v.y; a2 += d * v.z; a3 += d * v.w;
        }
        uint2 o;
        o.x = pack2bf(di * a0, di * a1);    // single bf16 quantization
        o.y = pack2bf(di * a2, di * a3);
        s_o1[rloc * 66 + lane] = o;
    }
    __syncthreads();

    // ---- GEMM from LDS tile: out = o1 @ W^T + b1 + b2 ----
    // Wave wid: cols [wid*32, wid*32+32), all 16 rows.
    {
        int m16  = lane & 15;
        int quad = lane >> 4;
        f32x4 acc0 = {0.f, 0.f, 0.f, 0.f};
        f32x4 acc1 = {0.f, 0.f, 0.f, 0.f};
        #pragma unroll
        for (int k0 = 0; k0 < CH; k0 += 32) {
            uint4 av = *(const uint4*)&s_o1[m16 * 66 + (k0 >> 2) + quad * 2];
            bf16x8 af = __builtin_bit_cast(bf16x8, av);
            const unsigned short* w0 = Wb + (size_t)(wid * 32 + m16) * CH + k0 + quad * 8;
            bf16x8 bv0 = *(const bf16x8*)w0;
            acc0 = __builtin_amdgcn_mfma_f32_16x16x32_bf16(af, bv0, acc0, 0, 0, 0);
            bf16x8 bv1 = *(const bf16x8*)(w0 + 16 * CH);
            acc1 = __builtin_amdgcn_mfma_f32_16x16x32_bf16(af, bv1, acc1, 0, 0, 0);
        }
        int rowB = bid * 16 + quad * 4;
        int col0 = wid * 32 + m16;
        float bb0 = b1[col0] + b2[col0];
        float bb1 = b1[col0 + 16] + b2[col0 + 16];
        #pragma unroll
        for (int r = 0; r < 4; ++r)
            out[(size_t)(rowB + r) * CH + col0] = acc0[r] + bb0;
        #pragma unroll
        for (int r = 0; r < 4; ++r)
            out[(size_t)(rowB + r) * CH + col0 + 16] = acc1[r] + bb1;
    }
}

extern "C" void kernel_launch(void* const* d_in, const int* in_sizes, int n_in,
                              void* d_out, int out_size, void* d_ws, size_t ws_size,
                              hipStream_t stream) {
    const float* x   = (const float*)d_in[0];   // (8192, 256)
    const float* W   = (const float*)d_in[1];   // (256, 256)
    const float* b1  = (const float*)d_in[2];   // (256,)
    const float* b2  = (const float*)d_in[3];   // (256,)
    const int*   ei  = (const int*)d_in[4];     // (2, E)
    int E = in_sizes[4] / 2;
    float* out = (float*)d_out;

    uint8_t* ws = (uint8_t*)d_ws;
    uint32_t*       bm  = (uint32_t*)ws;                                 // [0, 8 MB)
    int*            cnt = (int*)(ws + BM_BYTES);                         // 32 KB
    unsigned short* csr = (unsigned short*)(ws + BM_BYTES + 32 * 1024);  // 1 MB
    uint32_t*       Wb  = (uint32_t*)(ws + (10u << 20));                 // 128 KB

    // one memset covers bitmap + cnt (contiguous)
    hipMemsetAsync(bm, 0, BM_BYTES + 32 * 1024, stream);
    k_edges_wconv<<<EDGE_BLKS + 64, 256, 0, stream>>>(ei, bm, cnt, csr, E, W, Wb);
    k_agg_gemm<<<N_NODES / 16, 512, 0, stream>>>(cnt, csr, x, (const unsigned short*)Wb,
                                                 b1, b2, out);
}

// Round 10
// 98.415 us; speedup vs baseline: 1.0652x; 1.0652x over previous
//
#include <hip/hip_runtime.h>
#include <stdint.h>

#define N_NODES 8192
#define CH      256
#define NWORDS  256                    // 8192 bits / 32 per bitmap row
#define BM_WORDS (N_NODES * NWORDS)    // 2,097,152 words = 8 MB
#define LIST_CAP 192                   // per-wave neighbor cap (deg ~ Poisson(16); P(>192) ~ 0)

typedef short bf16x8 __attribute__((ext_vector_type(8)));
typedef float f32x4  __attribute__((ext_vector_type(4)));

static __device__ __forceinline__ unsigned short f2bf(float f) {
    union { float f; uint32_t u; } v; v.f = f;
    uint32_t r = v.u + 0x7fff + ((v.u >> 16) & 1);   // RNE
    return (unsigned short)(r >> 16);
}
static __device__ __forceinline__ uint32_t pack2bf(float lo, float hi) {
    return (uint32_t)f2bf(lo) | ((uint32_t)f2bf(hi) << 16);
}
static __device__ __forceinline__ float bfbits_lo(uint32_t u) {
    union { uint32_t u; float f; } v; v.u = u << 16; return v.f;
}
static __device__ __forceinline__ float bfbits_hi(uint32_t u) {
    union { uint32_t u; float f; } v; v.u = u & 0xffff0000u; return v.f;
}

// ---------------- scatter edges into bitmap (dedup via OR) ----------------
__global__ void k_edges(const int* __restrict__ ei, uint32_t* __restrict__ bm, int E) {
    int e = blockIdx.x * blockDim.x + threadIdx.x;
    if (e >= E) return;
    int r = ei[e];        // edge_index[0][e]
    int c = ei[E + e];    // edge_index[1][e]
    atomicOr(&bm[r * NWORDS + (c >> 5)], 1u << (c & 31));
}

// ---------------- fused: y = rsqrt(deg)*x (bf16 packed), Wb = bf16(W) ----------------
// blocks [0, 2048): 4 rows each (1 wave/row). blocks [2048, 2112): W conversion.
__global__ __launch_bounds__(256) void k_deg_y(const uint32_t* __restrict__ bm,
                                               const float* __restrict__ x,
                                               const float* __restrict__ W,
                                               uint32_t* __restrict__ y,
                                               uint32_t* __restrict__ Wb) {
    int lane = threadIdx.x & 63;
    int wid  = threadIdx.x >> 6;
    if (blockIdx.x < 2048) {
        int row = blockIdx.x * 4 + wid;
        uint4 w4 = ((const uint4*)(bm + (size_t)row * NWORDS))[lane];
        int cnt = __popc(w4.x) + __popc(w4.y) + __popc(w4.z) + __popc(w4.w);
        #pragma unroll
        for (int off = 1; off < 64; off <<= 1) cnt += __shfl_xor(cnt, off);
        float di = rsqrtf((float)(cnt + 1));
        float4 xv = ((const float4*)(x + (size_t)row * CH))[lane];
        uint2 o;
        o.x = pack2bf(di * xv.x, di * xv.y);
        o.y = pack2bf(di * xv.z, di * xv.w);
        ((uint2*)y)[row * 64 + lane] = o;
    } else {
        int i = (blockIdx.x - 2048) * 1024 + threadIdx.x * 4;   // 64 blocks cover 65536
        float4 wv = *(const float4*)(W + i);
        uint2 o;
        o.x = pack2bf(wv.x, wv.y);
        o.y = pack2bf(wv.z, wv.w);
        *(uint2*)(Wb + i / 2) = o;
    }
}

// ---------------- fused aggregate + GEMM (512 thr, 16 rows/block) ----------------
// Block b: aggregate rows [16b, 16b+16) into LDS (bf16) from the bitmap via a
// wave prefix-scan-built neighbor list, then MFMA GEMM the 16x256 tile vs W^T.
__global__ __launch_bounds__(512) void k_agg_gemm(
    const uint32_t* __restrict__ bm, const uint32_t* __restrict__ y,
    const unsigned short* __restrict__ Wb,
    const float* __restrict__ b1, const float* __restrict__ b2,
    float* __restrict__ out)
{
    const int tid  = threadIdx.x;
    const int bid  = blockIdx.x;
    const int lane = tid & 63;
    const int wid  = tid >> 6;              // 0..7

    __shared__ uint2 s_o1[16 * 66];                     // 16 rows x 256ch bf16 (+pad) 8.4 KB
    __shared__ __align__(8) unsigned short s_list[8][LIST_CAP];   // 3 KB

    const uint2* ys = (const uint2*)y;

    // ---- aggregate: 2 rows per wave, list + gather wave-private ----
    #pragma unroll
    for (int rr = 0; rr < 2; ++rr) {
        int rloc = wid * 2 + rr;
        int row  = bid * 16 + rloc;
        uint4 w4 = ((const uint4*)(bm + (size_t)row * NWORDS))[lane];
        int mycnt = __popc(w4.x) + __popc(w4.y) + __popc(w4.z) + __popc(w4.w);
        int pre = mycnt;                                 // inclusive scan
        #pragma unroll
        for (int off = 1; off < 64; off <<= 1) {
            int n = __shfl_up(pre, off);
            if (lane >= off) pre += n;
        }
        int total = __shfl(pre, 63);
        int p = pre - mycnt;                             // exclusive prefix
        uint32_t wrd[4] = {w4.x, w4.y, w4.z, w4.w};
        #pragma unroll
        for (int i = 0; i < 4; ++i) {
            uint32_t w = wrd[i];
            int basebit = lane * 128 + i * 32;
            while (w) {
                int b = __ffs(w) - 1;
                if (p < LIST_CAP) s_list[wid][p] = (unsigned short)(basebit + b);
                ++p;
                w &= (w - 1);
            }
        }
        float di = rsqrtf((float)(total + 1));

        uint2 d = ys[row * 64 + lane];                   // self (diagonal) term
        float a0 = bfbits_lo(d.x), a1 = bfbits_hi(d.x);
        float a2 = bfbits_lo(d.y), a3 = bfbits_hi(d.y);
        int cnt = total < LIST_CAP ? total : LIST_CAP;
        int k = 0;
        for (; k + 8 <= cnt; k += 8) {                   // 8 outstanding gathers
            uint2 dv[8];
            #pragma unroll
            for (int u = 0; u < 8; ++u)
                dv[u] = ys[(int)s_list[wid][k + u] * 64 + lane];
            #pragma unroll
            for (int u = 0; u < 8; ++u) {
                a0 += bfbits_lo(dv[u].x); a1 += bfbits_hi(dv[u].x);
                a2 += bfbits_lo(dv[u].y); a3 += bfbits_hi(dv[u].y);
            }
        }
        for (; k < cnt; ++k) {
            uint2 dd = ys[(int)s_list[wid][k] * 64 + lane];
            a0 += bfbits_lo(dd.x); a1 += bfbits_hi(dd.x);
            a2 += bfbits_lo(dd.y); a3 += bfbits_hi(dd.y);
        }
        uint2 o;
        o.x = pack2bf(di * a0, di * a1);
        o.y = pack2bf(di * a2, di * a3);
        s_o1[rloc * 66 + lane] = o;
    }
    __syncthreads();

    // ---- GEMM from LDS tile: out = o1 @ W^T + b1 + b2 ----
    // Wave wid: cols [wid*32, wid*32+32), all 16 rows.
    {
        int m16  = lane & 15;
        int quad = lane >> 4;
        f32x4 acc0 = {0.f, 0.f, 0.f, 0.f};
        f32x4 acc1 = {0.f, 0.f, 0.f, 0.f};
        #pragma unroll
        for (int k0 = 0; k0 < CH; k0 += 32) {
            uint4 av = *(const uint4*)&s_o1[m16 * 66 + (k0 >> 2) + quad * 2];
            bf16x8 af = __builtin_bit_cast(bf16x8, av);
            const unsigned short* w0 = Wb + (size_t)(wid * 32 + m16) * CH + k0 + quad * 8;
            bf16x8 bv0 = *(const bf16x8*)w0;
            acc0 = __builtin_amdgcn_mfma_f32_16x16x32_bf16(af, bv0, acc0, 0, 0, 0);
            bf16x8 bv1 = *(const bf16x8*)(w0 + 16 * CH);
            acc1 = __builtin_amdgcn_mfma_f32_16x16x32_bf16(af, bv1, acc1, 0, 0, 0);
        }
        int rowB = bid * 16 + quad * 4;
        int col0 = wid * 32 + m16;
        float bb0 = b1[col0] + b2[col0];
        float bb1 = b1[col0 + 16] + b2[col0 + 16];
        #pragma unroll
        for (int r = 0; r < 4; ++r)
            out[(size_t)(rowB + r) * CH + col0] = acc0[r] + bb0;
        #pragma unroll
        for (int r = 0; r < 4; ++r)
            out[(size_t)(rowB + r) * CH + col0 + 16] = acc1[r] + bb1;
    }
}

extern "C" void kernel_launch(void* const* d_in, const int* in_sizes, int n_in,
                              void* d_out, int out_size, void* d_ws, size_t ws_size,
                              hipStream_t stream) {
    const float* x   = (const float*)d_in[0];   // (8192, 256)
    const float* W   = (const float*)d_in[1];   // (256, 256)
    const float* b1  = (const float*)d_in[2];   // (256,)
    const float* b2  = (const float*)d_in[3];   // (256,)
    const int*   ei  = (const int*)d_in[4];     // (2, E)
    int E = in_sizes[4] / 2;
    float* out = (float*)d_out;

    uint8_t* ws = (uint8_t*)d_ws;
    uint32_t* bm = (uint32_t*)ws;                       // [0, 8 MB)
    uint32_t* y  = (uint32_t*)(ws + (8u << 20));        // [8, 12 MB) bf16 packed
    uint32_t* Wb = (uint32_t*)(ws + (12u << 20));       // 128 KB

    hipMemsetAsync(bm, 0, (size_t)BM_WORDS * 4, stream);
    k_edges<<<(E + 255) / 256, 256, 0, stream>>>(ei, bm, E);
    k_deg_y<<<2048 + 64, 256, 0, stream>>>(bm, x, W, y, Wb);
    k_agg_gemm<<<N_NODES / 16, 512, 0, stream>>>(bm, y, (const unsigned short*)Wb,
                                                 b1, b2, out);
}